// Round 13
// baseline (69.871 us; speedup 1.0000x reference)
//
#include <hip/hip_runtime.h>

// EDeeperGCN: out[e] = relu(cat(x[src],x[dst]) @ W1 + b1) @ W2 + b2
// AB[n] = [x[n]@W1_top + b1 | x[n]@W1_bot]  (f16, in d_ws)
// out[e] = relu(A[src[e]] + B[dst[e]]) @ W2 + b2
//
// Both GEMMs on mfma_f32_16x16x32_f16, proven fragment map:
//   lane = 16*g + r;  A: row r, k = 32*st + 8g + j;  B: col r, same k
//   C/D (HW, m89): col = lane&15, row = (lane>>4)*4 + reg
//
// r12 post-mortem: hand-pipelined asm rings keep collapsing (the register
// allocator aliases in-flight load buffers and inserts hidden waitcnts --
// VGPR_Count 52 < the 64 a live ring needs). The winning currency is
// resident_waves x lines_in_flight, so r13 goes MINIMAL: one 16-edge
// iteration per wave (8 line-perfect gathers grouped before compute, as the
// compiler naturally schedules), tiny body, huge grid (10000 blocks).

typedef _Float16 f16;
typedef _Float16 f16x8 __attribute__((ext_vector_type(8)));
typedef float    f32x4 __attribute__((ext_vector_type(4)));

#define HID  128
#define TWOH 256
#define OUTD 10

// ---------------- Kernel 0: pack weight fragments ----------------
// W1P: slot = T*4 + st (T = 16-col tile of W1cat), elem lane: j -> W1cat[32st+8g+j][T*16+r]
// W2P: slot = st*64 + lane: j -> W2[32st+8g+j][r] (0 if r>=10)
__global__ __launch_bounds__(256) void prep_weights(
    const float* __restrict__ W1,   // [256, 128]
    const float* __restrict__ W2,   // [128, 10]
    f16* __restrict__ W1P,          // 4096 slots x 8
    f16* __restrict__ W2P)          // 256 slots x 8
{
    const int slot = blockIdx.x * 256 + threadIdx.x;
    if (slot < 4096) {
        const int lane = slot & 63, i = slot >> 6;
        const int r = lane & 15, g = lane >> 4;
        const int T = i >> 2, st = i & 3;
        const int c = T * 16 + r;
        f16x8 v;
#pragma unroll
        for (int j = 0; j < 8; ++j) {
            const int k = st * 32 + g * 8 + j;
            const float w = (c < HID) ? W1[k * HID + c]
                                      : W1[(HID + k) * HID + (c - HID)];
            v[j] = (f16)w;
        }
        *(f16x8*)(W1P + (long)slot * 8) = v;
    } else if (slot < 4096 + 256) {
        const int s2 = slot - 4096;
        const int lane = s2 & 63, st = s2 >> 6;
        const int r = lane & 15, g = lane >> 4;
        f16x8 v;
#pragma unroll
        for (int j = 0; j < 8; ++j)
            v[j] = (r < OUTD) ? (f16)W2[(st * 32 + g * 8 + j) * OUTD + r] : (f16)0.f;
        *(f16x8*)(W2P + (long)s2 * 8) = v;
    }
}

// ---------------- Kernel 1: AB = x @ W1cat + [b1|0], f16 out, MFMA ----------------
// Block b: node tile b>>2 (16 nodes), col group b&3 (64 cols); wave = 16 cols.
__global__ __launch_bounds__(256, 6) void node_AB(
    const float* __restrict__ x,    // [N, 128]
    const f16* __restrict__ W1P,    // packed fragments
    const float* __restrict__ b1,   // [128]
    f16* __restrict__ AB,           // [N, 256]
    int n_nodes)
{
    const int t = threadIdx.x;
    const int lane = t & 63;
    const int r = lane & 15, g = lane >> 4;
    const int wv = t >> 6;
    const int n0 = (blockIdx.x >> 2) * 16;
    const int T = (blockIdx.x & 3) * 4 + wv;      // 16-col tile 0..15
    const int c = T * 16 + r;

    // x A-fragments first (latency starts early); 16 rows x 64B coalesced
    const int xrow = (n0 + r < n_nodes) ? (n0 + r) : (n_nodes - 1);
    float4 xl[4][2];
#pragma unroll
    for (int st = 0; st < 4; ++st) {
        const float* xp = x + (long)xrow * HID + st * 32 + g * 8;
        xl[st][0] = *(const float4*)xp;
        xl[st][1] = *(const float4*)(xp + 4);
    }

    // B-fragments: 4 coalesced b128 loads
    f16x8 w1f[4];
#pragma unroll
    for (int st = 0; st < 4; ++st)
        w1f[st] = *(const f16x8*)(W1P + ((long)(T * 4 + st) * 64 + lane) * 8);
    const float bias = (c < HID) ? b1[c] : 0.f;

    f32x4 acc = {0, 0, 0, 0};
#pragma unroll
    for (int st = 0; st < 4; ++st) {
        f16x8 a;
        a[0] = (f16)xl[st][0].x; a[1] = (f16)xl[st][0].y;
        a[2] = (f16)xl[st][0].z; a[3] = (f16)xl[st][0].w;
        a[4] = (f16)xl[st][1].x; a[5] = (f16)xl[st][1].y;
        a[6] = (f16)xl[st][1].z; a[7] = (f16)xl[st][1].w;
        acc = __builtin_amdgcn_mfma_f32_16x16x32_f16(a, w1f[st], acc, 0, 0, 0);
    }

#pragma unroll
    for (int q = 0; q < 4; ++q) {
        const int node = n0 + g * 4 + q;           // D row = node-within-tile
        if (node < n_nodes)
            AB[(long)node * TWOH + c] = (f16)(acc[q] + bias);
    }
}

// ---------------- Kernel 2: edge gather + relu + [128x10] GEMM, MFMA ----------------
// Block = 4 waves x 16 edges = 64 edges. One iteration per wave: 8 gathers
// (one aligned 64B line per edge per instr), 4 MFMA, store. No pipelining --
// concurrency comes from wave count (10000 blocks).
__global__ __launch_bounds__(256, 6) void edge_mlp(
    const f16* __restrict__ AB,     // [N, 256]
    const int* __restrict__ ei,     // [2, E]
    const f16* __restrict__ W2P,    // packed fragments
    const float* __restrict__ b2,   // [10]
    float* __restrict__ out,        // [E, 10]
    int n_edges)
{
    const int t = threadIdx.x;
    const int lane = t & 63;
    const int r = lane & 15, g = lane >> 4;
    const int wv = t >> 6;

    const long eb = (long)blockIdx.x * 64 + wv * 16;
    const long e = eb + r;
    const long ec = (e < n_edges) ? e : (n_edges - 1);
    const int sn = ei[ec];                         // 4-way broadcast across g
    const int dn = ei[(long)n_edges + ec];

    // 8 line-perfect gathers (grouped; compiler emits loads then counted waits)
    const f16* pa = AB + ((long)sn * TWOH + g * 8);
    const f16* pb = AB + ((long)dn * TWOH + HID + g * 8);
    f16x8 a0 = *(const f16x8*)pa;
    f16x8 a1 = *(const f16x8*)(pa + 32);
    f16x8 a2 = *(const f16x8*)(pa + 64);
    f16x8 a3 = *(const f16x8*)(pa + 96);
    f16x8 c0 = *(const f16x8*)pb;
    f16x8 c1 = *(const f16x8*)(pb + 32);
    f16x8 c2 = *(const f16x8*)(pb + 64);
    f16x8 c3 = *(const f16x8*)(pb + 96);

    // W2 B-fragment: 4 coalesced b128 loads (L2-hot, 4 KB total)
    f16x8 w2f[4];
#pragma unroll
    for (int st = 0; st < 4; ++st)
        w2f[st] = *(const f16x8*)(W2P + ((long)st * 64 + lane) * 8);
    const float bj = b2[(r < OUTD) ? r : 0];

    const f16x8 zt = {0, 0, 0, 0, 0, 0, 0, 0};
    f32x4 acc = {0, 0, 0, 0};
    f16x8 s;
    s = __builtin_elementwise_max(a0 + c0, zt);
    acc = __builtin_amdgcn_mfma_f32_16x16x32_f16(s, w2f[0], acc, 0, 0, 0);
    s = __builtin_elementwise_max(a1 + c1, zt);
    acc = __builtin_amdgcn_mfma_f32_16x16x32_f16(s, w2f[1], acc, 0, 0, 0);
    s = __builtin_elementwise_max(a2 + c2, zt);
    acc = __builtin_amdgcn_mfma_f32_16x16x32_f16(s, w2f[2], acc, 0, 0, 0);
    s = __builtin_elementwise_max(a3 + c3, zt);
    acc = __builtin_amdgcn_mfma_f32_16x16x32_f16(s, w2f[3], acc, 0, 0, 0);

    if (r < OUTD) {                                // D: col r = output j
#pragma unroll
        for (int q = 0; q < 4; ++q) {
            const long ee = eb + g * 4 + q;        // D row = edge-within-tile
            if (ee < n_edges)
                out[ee * OUTD + r] = acc[q] + bj;
        }
    }
}

extern "C" void kernel_launch(void* const* d_in, const int* in_sizes, int n_in,
                              void* d_out, int out_size, void* d_ws, size_t ws_size,
                              hipStream_t stream) {
    const float* x  = (const float*)d_in[0];
    const int*   ei = (const int*)d_in[1];
    const float* W1 = (const float*)d_in[2];
    const float* b1 = (const float*)d_in[3];
    const float* W2 = (const float*)d_in[4];
    const float* b2 = (const float*)d_in[5];
    float* out = (float*)d_out;

    const int n_nodes = in_sizes[0] / HID;          // 10000
    const int n_edges = in_sizes[1] / 2;            // 640000

    f16* AB  = (f16*)d_ws;                          // [n_nodes, 256] f16 = 5.12 MB
    f16* W1P = AB + (long)n_nodes * TWOH;           // 64 KB
    f16* W2P = W1P + 4096 * 8;                      // 4 KB

    prep_weights<<<17, 256, 0, stream>>>(W1, W2, W1P, W2P);

    node_AB<<<((n_nodes + 15) / 16) * 4, 256, 0, stream>>>(x, W1P, b1, AB, n_nodes);

    edge_mlp<<<(n_edges + 63) / 64, 256, 0, stream>>>(AB, ei, W2P, b2, out, n_edges);
}